// Round 5
// baseline (210.033 us; speedup 1.0000x reference)
//
#include <hip/hip_runtime.h>
#include <cstddef>

constexpr int NN  = 40000;   // nodes
constexpr int NE  = 640000;  // edges
constexpr int DIM = 128;     // D_IN == D_OUT
constexpr int CAP = 48;      // per-node neighbor capacity (max deg ~36 for Poisson(16))
constexpr int PLANE = NN * 64;  // shorts per 64-dim plane

typedef __attribute__((ext_vector_type(8))) short short8;   // 8 bf16 (4 VGPRs)
typedef __attribute__((ext_vector_type(4))) float floatx4;  // MFMA acc

// fp32 -> bf16 with round-to-nearest-even
__device__ __forceinline__ unsigned short f2bf(float x) {
    union { float f; unsigned int i; } v; v.f = x;
    unsigned int u = v.i;
    return (unsigned short)((u + 0x7fffu + ((u >> 16) & 1u)) >> 16);
}
__device__ __forceinline__ float bflo2f(unsigned int u) {   // low bf16 -> f32
    union { unsigned int i; float f; } v; v.i = u << 16; return v.f;
}
__device__ __forceinline__ float bfhi2f(unsigned int u) {   // high bf16 -> f32
    union { unsigned int i; float f; } v; v.i = u & 0xffff0000u; return v.f;
}

// ---------------------------------------------------------------------------
// Prep: [blocks 0..2499] cast feat fp32 -> bf16 planes featb[2][NN][64]
//       [blocks 2500..2627] transpose+cast W to Wc[4][128][64]
//       [blocks 2628..2784] zero cnt[NN]
// ---------------------------------------------------------------------------
__global__ __launch_bounds__(256) void k_prep(
    const float* __restrict__ feat, const float* __restrict__ Wself,
    const float* __restrict__ Wneigh, unsigned short* __restrict__ featb,
    unsigned short* __restrict__ Wc, int* __restrict__ cnt)
{
    int b = blockIdx.x, t = threadIdx.x;
    if (b < 2500) {
        int idx8 = b * 256 + t;          // 640000 groups of 8 elements
        int n  = idx8 >> 4;              // 16 groups per row
        int d0 = (idx8 & 15) << 3;       // dim base 0,8,...,120
        const float4* fp =
            reinterpret_cast<const float4*>(feat + (size_t)n * DIM + d0);
        float4 v0 = fp[0], v1 = fp[1];
        unsigned int p0 = (unsigned int)f2bf(v0.x) | ((unsigned int)f2bf(v0.y) << 16);
        unsigned int p1 = (unsigned int)f2bf(v0.z) | ((unsigned int)f2bf(v0.w) << 16);
        unsigned int p2 = (unsigned int)f2bf(v1.x) | ((unsigned int)f2bf(v1.y) << 16);
        unsigned int p3 = (unsigned int)f2bf(v1.z) | ((unsigned int)f2bf(v1.w) << 16);
        int plane = d0 >> 6, off = d0 & 63;
        *reinterpret_cast<uint4*>(
            featb + (size_t)plane * PLANE + (size_t)n * 64 + off) =
            make_uint4(p0, p1, p2, p3);
    } else if (b < 2628) {
        int idx = (b - 2500) * 256 + t;  // 0..32767
        int c = idx >> 13, n = (idx >> 6) & 127, kp = idx & 63;
        int k = c * 64 + kp;
        float w = (k < DIM) ? Wself[(size_t)k * DIM + n]
                            : Wneigh[(size_t)(k - DIM) * DIM + n];
        Wc[idx] = f2bf(w);
    } else {
        int i = (b - 2628) * 256 + t;
        if (i < NN) cnt[i] = 0;
    }
}

// ---------------------------------------------------------------------------
// Adjacency fill (r0 form — all restructurings measured equal; this one has
// minimal read traffic).
// ---------------------------------------------------------------------------
__global__ __launch_bounds__(256) void k_fill(
    const int* __restrict__ src, const int* __restrict__ dst,
    int* __restrict__ cnt, unsigned short* __restrict__ colf)
{
    int e = blockIdx.x * blockDim.x + threadIdx.x;
    if (e < NE) {
        int d = dst[e];
        int pos = atomicAdd(&cnt[d], 1);
        if (pos < CAP) colf[d * CAP + pos] = (unsigned short)src[e];
    }
}

// ---------------------------------------------------------------------------
// Fused gather+GEMM: out = [featb | h_neigh] (K=256 bf16) @ Wc + biases.
// 250 blocks x 160 rows, 5 waves. K-chunks c=0,1: stage featb plane c via
// global_load_lds (contiguous). K-chunks c=2,3: COMPUTE h_neigh plane (c-2)
// directly into As (fp32 accumulate -> bf16 pack) — removes the 41 MB hnb
// write+read round-trip and one kernel boundary.
// Gather MLP: waves process node PAIRS with up to 16 line-loads in flight
// (j=lane>>5 selects neighbor parity, u=lane&31 the dim-uint; one wave-load
// covers 2 neighbors' 128B rows). Bs staging is issued before the gather so
// it overlaps.
// ---------------------------------------------------------------------------
__global__ __launch_bounds__(320) void k_gg(
    const unsigned short* __restrict__ featb,  // [2][NN][64]
    const unsigned int* __restrict__ fb32,     // featb as [2][NN][32] uint
    const int* __restrict__ cnt,
    const unsigned short* __restrict__ colf,
    const unsigned short* __restrict__ Wc,     // [4][128][64]
    const float* __restrict__ bself, const float* __restrict__ bneigh,
    float* __restrict__ out)                   // [NN,128] fp32
{
    __shared__ unsigned short As[160 * 64];  // 20480 B
    __shared__ unsigned short Bs[128 * 64];  // 16384 B

    int t = threadIdx.x;
    int w = t >> 6;
    int lane = t & 63;
    int base_m = blockIdx.x * 160;

    floatx4 acc[2][8];
    #pragma unroll
    for (int a = 0; a < 2; ++a)
        #pragma unroll
        for (int b = 0; b < 8; ++b) acc[a][b] = (floatx4)0.f;

    unsigned int* As32 = reinterpret_cast<unsigned int*>(As);
    int j = lane >> 5;          // neighbor parity (gather phase)
    int u = lane & 31;          // dim-uint (gather phase)

    for (int c = 0; c < 4; ++c) {
        // ---- stage B chunk first (overlaps whatever A-phase does) ----
        if (t < 256) {
            const unsigned short* bp = Wc + (size_t)c * 128 * 64;
            #pragma unroll
            for (int it = 0; it < 4; ++it) {      // 1024 slots / 256 threads
                int slot = t + it * 256;
                __builtin_amdgcn_global_load_lds(
                    (const __attribute__((address_space(1))) unsigned int*)(bp + slot * 8),
                    (__attribute__((address_space(3))) unsigned int*)(Bs + slot * 8),
                    16, 0, 0);
            }
        }

        if (c < 2) {
            // ---- stage A chunk: featb plane c, contiguous 20480 B ----
            const unsigned short* srcp =
                featb + (size_t)c * PLANE + (size_t)base_m * 64;
            #pragma unroll
            for (int it = 0; it < 4; ++it) {      // 1280 slots / 320 threads
                int slot = t + it * 320;
                __builtin_amdgcn_global_load_lds(
                    (const __attribute__((address_space(1))) unsigned int*)(srcp + slot * 8),
                    (__attribute__((address_space(3))) unsigned int*)(As + slot * 8),
                    16, 0, 0);
            }
        } else {
            // ---- compute h_neigh plane (c-2) into As ----
            const unsigned int* pb = fb32 + (size_t)(c - 2) * (NN * 32);
            // wave w owns local nodes w*32 .. w*32+31; process in pairs
            for (int kk = 0; kk < 32; kk += 2) {
                int ln0 = w * 32 + kk, ln1 = ln0 + 1;
                int n0 = base_m + ln0, n1 = base_m + ln1;
                int deg0 = cnt[n0], deg1 = cnt[n1];
                int m0 = min(deg0, CAP), m1 = min(deg1, CAP);
                int sv0 = (lane < m0) ? (int)colf[n0 * CAP + lane] : 0;
                int sv1 = (lane < m1) ? (int)colf[n1 * CAP + lane] : 0;
                float ax0 = 0.f, ay0 = 0.f, ax1 = 0.f, ay1 = 0.f;
                // first batch: up to 16 neighbors per node, 16 loads in flight
                {
                    unsigned int va[8], vb_[8];
                    int ia[8], ib[8];
                    #pragma unroll
                    for (int q = 0; q < 8; ++q) {
                        ia[q] = 2 * q + j;
                        ib[q] = 2 * q + j;
                        int sa = __shfl(sv0, ia[q]);
                        int sb = __shfl(sv1, ib[q]);
                        va[q]  = pb[sa * 32 + u];
                        vb_[q] = pb[sb * 32 + u];
                    }
                    #pragma unroll
                    for (int q = 0; q < 8; ++q) {
                        if (ia[q] < m0) { ax0 += bflo2f(va[q]);  ay0 += bfhi2f(va[q]); }
                        if (ib[q] < m1) { ax1 += bflo2f(vb_[q]); ay1 += bfhi2f(vb_[q]); }
                    }
                }
                // tail batches (deg > 16; rare)
                for (int i = 16; i < m0; i += 16) {
                    unsigned int va[8]; int ia[8];
                    #pragma unroll
                    for (int q = 0; q < 8; ++q) {
                        ia[q] = i + 2 * q + j;
                        int sa = __shfl(sv0, ia[q] < CAP ? ia[q] : 0);
                        va[q] = pb[sa * 32 + u];
                    }
                    #pragma unroll
                    for (int q = 0; q < 8; ++q)
                        if (ia[q] < m0) { ax0 += bflo2f(va[q]); ay0 += bfhi2f(va[q]); }
                }
                for (int i = 16; i < m1; i += 16) {
                    unsigned int vb2[8]; int ib[8];
                    #pragma unroll
                    for (int q = 0; q < 8; ++q) {
                        ib[q] = i + 2 * q + j;
                        int sb = __shfl(sv1, ib[q] < CAP ? ib[q] : 0);
                        vb2[q] = pb[sb * 32 + u];
                    }
                    #pragma unroll
                    for (int q = 0; q < 8; ++q)
                        if (ib[q] < m1) { ax1 += bflo2f(vb2[q]); ay1 += bfhi2f(vb2[q]); }
                }
                // combine the two neighbor-parity halves
                ax0 += __shfl_xor(ax0, 32); ay0 += __shfl_xor(ay0, 32);
                ax1 += __shfl_xor(ax1, 32); ay1 += __shfl_xor(ay1, 32);
                if (lane < 32) {
                    float inv0 = 1.0f / fmaxf((float)deg0, 1.0f);
                    float inv1 = 1.0f / fmaxf((float)deg1, 1.0f);
                    As32[ln0 * 32 + u] = (unsigned int)f2bf(ax0 * inv0)
                                       | ((unsigned int)f2bf(ay0 * inv0) << 16);
                    As32[ln1 * 32 + u] = (unsigned int)f2bf(ax1 * inv1)
                                       | ((unsigned int)f2bf(ay1 * inv1) << 16);
                }
            }
        }
        __syncthreads();   // drains vmcnt (global_load_lds) + lgkm (ds_write)

        // ---- 2 k-steps of 32 ----
        #pragma unroll
        for (int s = 0; s < 2; ++s) {
            int koff = s * 32 + (lane >> 4) * 8;
            short8 af[2];
            #pragma unroll
            for (int mt = 0; mt < 2; ++mt) {
                int m = w * 32 + mt * 16 + (lane & 15);
                af[mt] = *reinterpret_cast<const short8*>(As + m * 64 + koff);
            }
            #pragma unroll
            for (int nt = 0; nt < 8; ++nt) {
                int n = nt * 16 + (lane & 15);
                short8 bf = *reinterpret_cast<const short8*>(Bs + n * 64 + koff);
                acc[0][nt] = __builtin_amdgcn_mfma_f32_16x16x32_bf16(
                    af[0], bf, acc[0][nt], 0, 0, 0);
                acc[1][nt] = __builtin_amdgcn_mfma_f32_16x16x32_bf16(
                    af[1], bf, acc[1][nt], 0, 0, 0);
            }
        }
        __syncthreads();
    }

    // ---- epilogue: C/D layout col=lane&15, row=(lane>>4)*4+reg ----
    int colb = lane & 15;
    int quad = lane >> 4;
    #pragma unroll
    for (int nt = 0; nt < 8; ++nt) {
        int col = nt * 16 + colb;
        float bb = bself[col] + bneigh[col];
        #pragma unroll
        for (int mt = 0; mt < 2; ++mt) {
            #pragma unroll
            for (int r = 0; r < 4; ++r) {
                int row = base_m + w * 32 + mt * 16 + quad * 4 + r;
                out[(size_t)row * DIM + col] = acc[mt][nt][r] + bb;
            }
        }
    }
}

// ---------------------------------------------------------------------------
extern "C" void kernel_launch(void* const* d_in, const int* in_sizes, int n_in,
                              void* d_out, int out_size, void* d_ws, size_t ws_size,
                              hipStream_t stream)
{
    const float* feat   = (const float*)d_in[0];
    const int*   src    = (const int*)d_in[1];
    const int*   dst    = (const int*)d_in[2];
    const float* Wself  = (const float*)d_in[3];
    const float* bself  = (const float*)d_in[4];
    const float* Wneigh = (const float*)d_in[5];
    const float* bneigh = (const float*)d_in[6];
    float* out = (float*)d_out;

    // Workspace layout (bytes):
    //   featb [2][NN][64] bf16 @ 0           (10,240,000)
    //   colf  [NN][CAP]   u16  @ 10,240,000  ( 3,840,000)
    //   Wc    [4][128][64]bf16 @ 14,080,000  (    65,536)
    //   cnt   [NN]        i32  @ 14,145,536  (   160,000)
    // total 14,305,536 B   (hnb eliminated)
    char* ws = (char*)d_ws;
    unsigned short* featb = (unsigned short*)(ws);
    unsigned short* colf  = (unsigned short*)(ws + 10240000);
    unsigned short* Wc    = (unsigned short*)(ws + 14080000);
    int*            cnt   = (int*)(ws + 14145536);

    k_prep<<<2785, 256, 0, stream>>>(feat, Wself, Wneigh, featb, Wc, cnt);

    k_fill<<<(NE + 255) / 256, 256, 0, stream>>>(src, dst, cnt, colf);

    k_gg<<<NN / 160, 320, 0, stream>>>(
        featb, (const unsigned int*)featb, cnt, colf, Wc, bself, bneigh, out);
}